// Round 3
// baseline (205.256 us; speedup 1.0000x reference)
//
#include <hip/hip_runtime.h>

// ClusterDiceLoss: segmented dice over 64 clusters of a 256^3 volume.
// Memory floor: 201 MB read (FETCH ~100 MB after L3 hits) -> ~30 us.
// R3 (76us)/R4 (78us)/R5 (73us): all pipes idle; time invariant to memory
//   source (L3-warm replays = same 72us), LDS conflicts (2.2M->1.3M, no
//   change), and global-atomic contention (64x less, -5us). The only
//   invariant op: one LDS atomicAdd per element = 1024 wave ds_add per CU
//   -> ~168 cyc per wave64 scattered LDS atomic (lane-serial RMW, not
//   counted as bank conflict). That is the whole kernel.
// R6: eliminate LDS atomics. Only union=sum(sp+st) and inter=sum(sp&st) are
//   needed (not sp/st separately): per-thread per-bin fits u16
//   (inter<<8|union, bounds 64/128 at 64 elems/thread). Fully private
//   [65][256] u16 histogram = 33 KB -> 4 blocks/CU, plain
//   ds_read_u16+add+ds_write_b16 (~6cyc pipe each, 12k cyc/CU total,
//   hidden under the load stream). [bin][thread] layout -> bank=(tid>>1)%32,
//   uniform 2-way = free. 1024 blocks: all resident, one generation,
//   single fold per block.

#define NBIN 65          // bins 0..64 (bin 0 = background, never folded)
#define NREP 64          // replicated global partial arrays (R5, keep)
#define REP_MASK 63
#define BLOCKS 1024
#define THREADS 256

// per-element contribution: inter<<8 | (sp+st). Per-thread bounds at 64
// elements/thread: union-field <= 128 < 256, inter-field <= 64. No carry.
__device__ __forceinline__ unsigned short contrib16(float p, float t) {
    unsigned int sp = (p != 0.0f) ? 1u : 0u;
    unsigned int st = (t != 0.0f) ? 1u : 0u;
    return (unsigned short)(((sp & st) << 8) | (sp + st));
}

// col = &s_hist[0][tid]; bin b lives at col[b*THREADS]. Non-atomic RMW:
// this thread is the only writer of its column.
__device__ __forceinline__ void rmw4(unsigned short* col, float4 p, float4 t, int4 l) {
    col[l.x * THREADS] = (unsigned short)(col[l.x * THREADS] + contrib16(p.x, t.x));
    col[l.y * THREADS] = (unsigned short)(col[l.y * THREADS] + contrib16(p.y, t.y));
    col[l.z * THREADS] = (unsigned short)(col[l.z * THREADS] + contrib16(p.z, t.z));
    col[l.w * THREADS] = (unsigned short)(col[l.w * THREADS] + contrib16(p.w, t.w));
}

__global__ __launch_bounds__(THREADS, 4) void seg_count_kernel(
    const float* __restrict__ pred,
    const float* __restrict__ target,
    const int* __restrict__ labels,
    unsigned long long* __restrict__ part,   // [64][NREP] packed u64, zeroed
    int n)
{
    // [bin][thread] u16: main-phase bank = (tid>>1)%32 (2-way, free);
    // fold reads are contiguous per bin row.
    __shared__ unsigned short s_hist[NBIN][THREADS];   // 33280 B
    const int tid = threadIdx.x;
    const int rep = (int)blockIdx.x & REP_MASK;

    unsigned int* hz = (unsigned int*)s_hist;
    for (int i = tid; i < NBIN * THREADS / 2; i += THREADS) hz[i] = 0u;
    __syncthreads();

    const int n_vec = n >> 2;  // float4 groups
    const float4* __restrict__ p4 = (const float4*)pred;
    const float4* __restrict__ t4 = (const float4*)target;
    const int4*   __restrict__ l4 = (const int4*)labels;

    // contiguous chunk per block: 4096 groups -> 16 per thread, 4 batches.
    const int chunk = (n_vec + (int)gridDim.x - 1) / (int)gridDim.x;
    const int base = blockIdx.x * chunk;
    const int end = min(base + chunk, n_vec);

    unsigned short* col = &s_hist[0][tid];

    int idx = base + tid;
    for (; idx + 3 * THREADS < end; idx += 4 * THREADS) {
        float4 p0 = p4[idx];
        float4 p1 = p4[idx + THREADS];
        float4 p2 = p4[idx + 2 * THREADS];
        float4 p3 = p4[idx + 3 * THREADS];
        float4 t0 = t4[idx];
        float4 t1 = t4[idx + THREADS];
        float4 t2 = t4[idx + 2 * THREADS];
        float4 t3 = t4[idx + 3 * THREADS];
        int4   l0 = l4[idx];
        int4   l1 = l4[idx + THREADS];
        int4   l2 = l4[idx + 2 * THREADS];
        int4   l3 = l4[idx + 3 * THREADS];
        __builtin_amdgcn_sched_barrier(0);
        rmw4(col, p0, t0, l0);
        rmw4(col, p1, t1, l1);
        rmw4(col, p2, t2, l2);
        rmw4(col, p3, t3, l3);
    }
    for (; idx < end; idx += THREADS)
        rmw4(col, p4[idx], t4[idx], l4[idx]);

    // scalar tail (n not divisible by 4): block 0 only; private column -> safe
    if (blockIdx.x == 0) {
        for (int i = (n_vec << 2) + tid; i < n; i += THREADS)
            col[labels[i] * THREADS] =
                (unsigned short)(col[labels[i] * THREADS] + contrib16(pred[i], target[i]));
    }
    __syncthreads();

    // Fold: bins 1..64 x 4 partial-threads (bin 0 dropped -> exactly 256).
    // Thread (s,q) sums copies q*64..q*64+63 via 16 u64 reads (4 u16 each),
    // SWAR-accumulated in 16-bit lanes (16 iters x 255 max = 4080 < 65536).
    const int s = 1 + (tid >> 2);
    const int q = tid & 3;
    const unsigned long long* row = (const unsigned long long*)&s_hist[s][q * 64];
    unsigned long long accU = 0, accI = 0;
    const int rot = tid & 15;   // rotate start to dodge lockstep banking
    #pragma unroll
    for (int j = 0; j < 16; ++j) {
        int i = (j + rot) & 15;
        unsigned long long v = row[i];
        accU += v & 0x00FF00FF00FF00FFull;
        accI += (v >> 8) & 0x00FF00FF00FF00FFull;
    }
    accU += accU >> 32;   // two u16 lanes, each <= 8160: no cross-lane carry
    accI += accI >> 32;
    unsigned int U = ((unsigned int)accU & 0xFFFFu) + (((unsigned int)accU >> 16) & 0xFFFFu);
    unsigned int I = ((unsigned int)accI & 0xFFFFu) + (((unsigned int)accI >> 16) & 0xFFFFu);

    // combine the 4 quarter-sums (adjacent lanes), one atomic per bin.
    U += __shfl_xor(U, 1); U += __shfl_xor(U, 2);
    I += __shfl_xor(I, 1); I += __shfl_xor(I, 2);
    if (q == 0) {
        // per-replica bounds: 16 blocks x (U<=32768) = 524k << 2^32
        unsigned long long tot = ((unsigned long long)I << 32) | (unsigned long long)U;
        if (tot) atomicAdd(&part[(s - 1) * NREP + rep], tot);
    }
}

__global__ __launch_bounds__(256) void dice_finalize_kernel(
    const unsigned long long* __restrict__ part,   // [64][NREP]
    const int* __restrict__ nc_ptr,
    float* __restrict__ out)
{
    const int nc = *nc_ptr;          // 64
    const int tid = threadIdx.x;
    const int s = 1 + (tid >> 2);
    const int q = tid & 3;

    unsigned long long acc = 0;
    const unsigned long long* row = part + (s - 1) * NREP + q * 16;
    #pragma unroll
    for (int i = 0; i < 16; ++i) acc += row[i];
    acc += __shfl_xor(acc, 1);
    acc += __shfl_xor(acc, 2);

    __shared__ float s_dice[64];
    if (q == 0) {
        float U = (float)(unsigned int)(acc & 0xFFFFFFFFull);
        float I = (float)(unsigned int)(acc >> 32);
        // reference: where(union>0, 2*inter/max(union,1), 1); union integer
        float dice = (U > 0.0f) ? (2.0f * I / U) : 1.0f;
        s_dice[s - 1] = (s <= nc) ? dice : 0.0f;
    }
    __syncthreads();

    if (tid < 64) {
        float local = s_dice[tid];
        #pragma unroll
        for (int off = 32; off > 0; off >>= 1)
            local += __shfl_down(local, off);
        if (tid == 0) out[0] = 1.0f - local / (float)nc;
    }
}

extern "C" void kernel_launch(void* const* d_in, const int* in_sizes, int n_in,
                              void* d_out, int out_size, void* d_ws, size_t ws_size,
                              hipStream_t stream) {
    const float* pred   = (const float*)d_in[0];
    const float* target = (const float*)d_in[1];
    const int*   labels = (const int*)d_in[2];
    const int*   nc_ptr = (const int*)d_in[3];
    float* out = (float*)d_out;
    unsigned long long* part = (unsigned long long*)d_ws;

    const int n = in_sizes[0];

    hipMemsetAsync(d_ws, 0, 64 * NREP * sizeof(unsigned long long), stream);

    seg_count_kernel<<<BLOCKS, THREADS, 0, stream>>>(
        pred, target, labels, part, n);
    dice_finalize_kernel<<<1, 256, 0, stream>>>(part, nc_ptr, out);
}

// Round 5
// 202.906 us; speedup vs baseline: 1.0116x; 1.0116x over previous
//
#include <hip/hip_runtime.h>

// ClusterDiceLoss: segmented dice over 64 clusters of a 256^3 volume.
// Memory floor: 201 MB logical read -> ~32 us at 6.3 TB/s.
// History: R3 (76us, LDS u64 atomics) = R4 (78us, u32 atomics, 16 copies) =
//   R5 (73us, +spread global atomics) = R6 (77us, non-atomic u16 RMW, 2x DS
//   ops). Time invariant to memory source (L3-warm == cold), bank conflicts,
//   atomic vs non-atomic, DS op count. All pipes <20% busy. => latency-
//   exposure bound, and VGPR 36/44/56/52 proves regalloc collapsed the load
//   window to ~2-3 in flight every single round.
// R7: inline-asm loads + tied-operand vmcnt waits -> COMPILE FAIL ("tied
//   indirect register inputs" on "+v" of array elements).
// R8: same design, legal asm:
//   - loads: volatile "global_load_dwordx4 %0, %1, %2" (cannot be collapsed,
//     CSE'd, or reordered vs other volatile asm) into NAMED registers
//     (no arrays -> no scratch risk, rule #20);
//   - waits: asm volatile("s_waitcnt vmcnt(N)" ::: "memory") followed by
//     __builtin_amdgcn_sched_barrier(0) so consumers can't hoist above the
//     wait (rule #18);
//   - 2-deep batch pipeline: 24 loads (384 B/lane) in flight, one wait per
//     12-load batch, never vmcnt(0) until the tail;
//   - __launch_bounds__(256,3): ~168 VGPR cap, headroom so the 96 data
//     VGPRs never spill (scratch ops would corrupt vmcnt counting).
//   - R7's batched-read cascaded-merge RMW: one DS round trip per 4 elems.

#define NBIN 65          // bins 0..64 (bin 0 = background, dropped at fold)
#define NREP 64          // replicated global partial slots
#define REP_MASK 63
#define BLOCKS 1024
#define THREADS 256

typedef float4 f4;
typedef int4 i4;

// one 16-B load, 32-bit voffset + 64-bit SGPR base; volatile => pinned.
#define GLOAD(dst, voff, base) \
    asm volatile("global_load_dwordx4 %0, %1, %2" \
                 : "=v"(dst) : "v"(voff), "s"(base))

// wait for all but the newest NSTR outstanding vector loads, then fence the
// scheduler so no consumer is hoisted above the wait (rule #18).
#define WAITN(NSTR) do { \
    asm volatile("s_waitcnt vmcnt(" NSTR ")" ::: "memory"); \
    __builtin_amdgcn_sched_barrier(0); \
} while (0)

// issue one 12-load batch (4 groups x {pred,target,labels}) at vo0..vo3
#define ISSUE(X) do { \
    GLOAD(P##X##0, vo0, pred);   GLOAD(P##X##1, vo1, pred); \
    GLOAD(P##X##2, vo2, pred);   GLOAD(P##X##3, vo3, pred); \
    GLOAD(T##X##0, vo0, target); GLOAD(T##X##1, vo1, target); \
    GLOAD(T##X##2, vo2, target); GLOAD(T##X##3, vo3, target); \
    GLOAD(L##X##0, vo0, labels); GLOAD(L##X##1, vo1, labels); \
    GLOAD(L##X##2, vo2, labels); GLOAD(L##X##3, vo3, labels); \
} while (0)

#define ADV() do { vo0 += 16384u; vo1 += 16384u; vo2 += 16384u; vo3 += 16384u; } while (0)

#define PROCESS(X) do { \
    rmw_group(hist, tid, P##X##0, T##X##0, L##X##0); \
    rmw_group(hist, tid, P##X##1, T##X##1, L##X##1); \
    rmw_group(hist, tid, P##X##2, T##X##2, L##X##2); \
    rmw_group(hist, tid, P##X##3, T##X##3, L##X##3); \
} while (0)

// per-element u16 contribution: inter<<8 | (sp+st). 64 elems/thread ->
// union field <= 128 < 256, inter <= 64. No carry.
__device__ __forceinline__ unsigned int contrib(float p, float t) {
    unsigned int sp = (p != 0.0f) ? 1u : 0u;
    unsigned int st = (t != 0.0f) ? 1u : 0u;
    return ((sp & st) << 8) | (sp + st);
}

// Batched-read cascaded-merge RMW into this thread's private column
// ([bin][thread] u16; sole writer of its cells). All 4 reads precede all 4
// writes (one lgkmcnt exposure per 4 elements). Duplicate labels within the
// group: each later duplicate's write carries the cumulative sum (e-cascade);
// same-wave DS ops retire in order, so the last write is the correct total.
__device__ __forceinline__ void rmw_group(unsigned short* hist, int tid,
                                          f4 p, f4 t, i4 l) {
    const int i0 = l.x * THREADS + tid;
    const int i1 = l.y * THREADS + tid;
    const int i2 = l.z * THREADS + tid;
    const int i3 = l.w * THREADS + tid;
    const unsigned int d0 = hist[i0];
    const unsigned int d1 = hist[i1];
    const unsigned int d2 = hist[i2];
    const unsigned int d3 = hist[i3];
    const unsigned int c0 = contrib(p.x, t.x);
    const unsigned int c1 = contrib(p.y, t.y);
    const unsigned int c2 = contrib(p.z, t.z);
    const unsigned int c3 = contrib(p.w, t.w);
    const unsigned int e0 = c0;
    const unsigned int e1 = c1 + ((i1 == i0) ? e0 : 0u);
    const unsigned int e2 = c2 + ((i2 == i1) ? e1 : ((i2 == i0) ? e0 : 0u));
    const unsigned int e3 = c3 + ((i3 == i2) ? e2 :
                             ((i3 == i1) ? e1 : ((i3 == i0) ? e0 : 0u)));
    hist[i0] = (unsigned short)(d0 + e0);
    hist[i1] = (unsigned short)(d1 + e1);
    hist[i2] = (unsigned short)(d2 + e2);
    hist[i3] = (unsigned short)(d3 + e3);
}

__global__ __launch_bounds__(THREADS, 3) void seg_count_kernel(
    const float* __restrict__ pred,
    const float* __restrict__ target,
    const int* __restrict__ labels,
    unsigned long long* __restrict__ part,   // [64][NREP] packed u64, zeroed
    int n)
{
    __shared__ unsigned short s_hist[NBIN][THREADS];   // 33280 B
    const int tid = threadIdx.x;
    const int rep = (int)blockIdx.x & REP_MASK;
    unsigned short* hist = &s_hist[0][0];

    unsigned int* hz = (unsigned int*)s_hist;
    for (int i = tid; i < NBIN * THREADS / 2; i += THREADS) hz[i] = 0u;
    __syncthreads();

    const int n_vec = n >> 2;  // float4 groups
    const int chunk = (n_vec + (int)gridDim.x - 1) / (int)gridDim.x;
    const int base = blockIdx.x * chunk;
    const int end = min(base + chunk, n_vec);

    if (end - base == 16 * THREADS) {
        // ---- fast path: 16 groups/thread = 4 batches of 4, 2-deep pipe ----
        f4 PA0, PA1, PA2, PA3, TA0, TA1, TA2, TA3;
        f4 PB0, PB1, PB2, PB3, TB0, TB1, TB2, TB3;
        i4 LA0, LA1, LA2, LA3, LB0, LB1, LB2, LB3;
        unsigned int vo0 = (unsigned int)(base + tid) * 16u;
        unsigned int vo1 = vo0 + 4096u;
        unsigned int vo2 = vo0 + 8192u;
        unsigned int vo3 = vo0 + 12288u;

        ISSUE(A);                    // batch 0 in flight (12)
        ADV();
        ISSUE(B);                    // batch 1 in flight (24)
        WAITN("12");                 // batch 0 done
        PROCESS(A);
        ADV();
        ISSUE(A);                    // batch 2 in flight (24)
        WAITN("12");                 // batch 1 done
        PROCESS(B);
        ADV();
        ISSUE(B);                    // batch 3 in flight (24)
        WAITN("12");                 // batch 2 done
        PROCESS(A);
        WAITN("0");                  // batch 3 done
        PROCESS(B);
    } else {
        // ---- generic fallback (not hit at n = 256^3 / 1024 blocks) ----
        const f4* __restrict__ p4 = (const f4*)pred;
        const f4* __restrict__ t4 = (const f4*)target;
        const i4* __restrict__ l4 = (const i4*)labels;
        for (int idx = base + tid; idx < end; idx += THREADS)
            rmw_group(hist, tid, p4[idx], t4[idx], l4[idx]);
    }

    // scalar tail (n not divisible by 4): block 0 only; private column
    if (blockIdx.x == 0) {
        for (int i = (n_vec << 2) + tid; i < n; i += THREADS)
            hist[labels[i] * THREADS + tid] =
                (unsigned short)(hist[labels[i] * THREADS + tid] +
                                 contrib(pred[i], target[i]));
    }
    __syncthreads();

    // Fold: bins 1..64 x 4 quarter-threads (bin 0 dropped -> exactly 256).
    // 16 u64 reads (4 u16 each), SWAR 16-bit lanes: 16 iters x 255 < 65536.
    const int s = 1 + (tid >> 2);
    const int q = tid & 3;
    const unsigned long long* row =
        (const unsigned long long*)&s_hist[s][q * 64];
    unsigned long long accU = 0, accI = 0;
    const int rot = tid & 15;   // rotate start to dodge lockstep banking
    #pragma unroll
    for (int j = 0; j < 16; ++j) {
        int i = (j + rot) & 15;
        unsigned long long v = row[i];
        accU += v & 0x00FF00FF00FF00FFull;
        accI += (v >> 8) & 0x00FF00FF00FF00FFull;
    }
    accU += accU >> 32;   // u16 lanes <= 8160: no cross-lane carry
    accI += accI >> 32;
    unsigned int U = ((unsigned int)accU & 0xFFFFu) + (((unsigned int)accU >> 16) & 0xFFFFu);
    unsigned int I = ((unsigned int)accI & 0xFFFFu) + (((unsigned int)accI >> 16) & 0xFFFFu);

    U += __shfl_xor(U, 1); U += __shfl_xor(U, 2);
    I += __shfl_xor(I, 1); I += __shfl_xor(I, 2);
    if (q == 0) {
        unsigned long long tot =
            ((unsigned long long)I << 32) | (unsigned long long)U;
        if (tot) atomicAdd(&part[(s - 1) * NREP + rep], tot);
    }
}

__global__ __launch_bounds__(256) void dice_finalize_kernel(
    const unsigned long long* __restrict__ part,   // [64][NREP]
    const int* __restrict__ nc_ptr,
    float* __restrict__ out)
{
    const int nc = *nc_ptr;          // 64
    const int tid = threadIdx.x;
    const int s = 1 + (tid >> 2);
    const int q = tid & 3;

    unsigned long long acc = 0;
    const unsigned long long* row = part + (s - 1) * NREP + q * 16;
    #pragma unroll
    for (int i = 0; i < 16; ++i) acc += row[i];
    acc += __shfl_xor(acc, 1);
    acc += __shfl_xor(acc, 2);

    __shared__ float s_dice[64];
    if (q == 0) {
        float U = (float)(unsigned int)(acc & 0xFFFFFFFFull);
        float I = (float)(unsigned int)(acc >> 32);
        float dice = (U > 0.0f) ? (2.0f * I / U) : 1.0f;
        s_dice[s - 1] = (s <= nc) ? dice : 0.0f;
    }
    __syncthreads();

    if (tid < 64) {
        float local = s_dice[tid];
        #pragma unroll
        for (int off = 32; off > 0; off >>= 1)
            local += __shfl_down(local, off);
        if (tid == 0) out[0] = 1.0f - local / (float)nc;
    }
}

extern "C" void kernel_launch(void* const* d_in, const int* in_sizes, int n_in,
                              void* d_out, int out_size, void* d_ws, size_t ws_size,
                              hipStream_t stream) {
    const float* pred   = (const float*)d_in[0];
    const float* target = (const float*)d_in[1];
    const int*   labels = (const int*)d_in[2];
    const int*   nc_ptr = (const int*)d_in[3];
    float* out = (float*)d_out;
    unsigned long long* part = (unsigned long long*)d_ws;

    const int n = in_sizes[0];

    hipMemsetAsync(d_ws, 0, 64 * NREP * sizeof(unsigned long long), stream);

    seg_count_kernel<<<BLOCKS, THREADS, 0, stream>>>(
        pred, target, labels, part, n);
    dice_finalize_kernel<<<1, 256, 0, stream>>>(part, nc_ptr, out);
}